// Round 4
// baseline (191.567 us; speedup 1.0000x reference)
//
#include <hip/hip_runtime.h>

// STDP delta_w on MI355X, bf16-MFMA formulation.
//   term1: dW1[o,p] = sum_k O[k,o]*TP[k,p], K = T*B = 1024  -> bf16 MFMA GEMM
//   term2: -coef[o]*W[o,p], coef[o] = sum_k O[k,o]*PO[k,o]  -> fp32 epilogue
//
// Converter (rewritten R4): block = all 16 b x 32 p slab. Per 8-t chunk:
//   stage fp32 via global_load_lds w16 (coalesced, no VGPR round-trip) ->
//   recurrence from LDS (2 chains/thread) -> bf16 [k][p] LDS tile ->
//   16-B k-contiguous flush to plain [x][k] global (GEMM-ready layout).
//
// ws: AT bf16 [4096][1024] (8MB) | BT bf16 [4096][1024] (8MB) | coef f32[4096]

#define T_STEPS 64
#define B_SZ    16
#define PRE     4096
#define POST    4096
#define K_TOT   1024

typedef __attribute__((ext_vector_type(8))) unsigned short ushort8;
typedef __attribute__((ext_vector_type(8))) __bf16 bf16x8;
typedef __attribute__((ext_vector_type(4))) float floatx4;

__device__ __forceinline__ unsigned short f2bf(float f) {
    unsigned int u = __float_as_uint(f);
    u += 0x7fff + ((u >> 16) & 1);          // round-to-nearest-even
    return (unsigned short)(u >> 16);
}

__device__ __forceinline__ void glds16(const void* g, void* l) {
    __builtin_amdgcn_global_load_lds((const __attribute__((address_space(1))) void*)g,
                                     (__attribute__((address_space(3))) void*)l,
                                     16, 0, 0);
}

// ---------------------------------------------------------------------------
// Converter: grid = 256 blocks (matrix = blk>>7, p-chunk = blk&127), 256 thr.
__global__ __launch_bounds__(256) void trace_convert(
        const float* __restrict__ in_spikes,
        const float* __restrict__ out_spikes,
        unsigned short* __restrict__ AT,
        unsigned short* __restrict__ BT,
        float* __restrict__ coef) {
    __shared__ float ldsf[4096];             // [8 t][16 b][32 p] fp32, 16 KB
    __shared__ unsigned short ot[128 * 34];  // [128 k][32 p + 2 pad], 8.5 KB
    __shared__ float cbuf[8][33];
    const int tid  = threadIdx.x;
    const int wave = tid >> 6;
    const int lane = tid & 63;
    const bool isA = blockIdx.x >= 128;
    const int p0 = (blockIdx.x & 127) * 32;
    const float* src = isA ? out_spikes : in_spikes;
    unsigned short* dst = isA ? AT : BT;

    const int bA = tid >> 5;                 // chains (bA, p) and (bA+8, p)
    const int pA = tid & 31;

    float st0 = 0.f, st1 = 0.f, c0 = 0.f, c1 = 0.f;

    for (int tc = 0; tc < 8; ++tc) {
        const int T0 = tc * 8;
        // ---- stage 16 b x 8 t x 32 p fp32 into LDS (4 glds x16B per wave)
        #pragma unroll
        for (int i = 0; i < 4; ++i) {
            const int q  = (wave * 4 + i) * 64 + lane;  // float-quad id 0..1023
            const int p  = (q & 7) * 4;
            const int b  = (q >> 3) & 15;
            const int tl = q >> 7;
            const float* g = src + ((size_t)((T0 + tl) * 16 + b)) * 4096 + p0 + p;
            glds16(g, (char*)ldsf + (size_t)(wave * 4 + i) * 1024);
        }
        __syncthreads();                     // drains vmcnt

        // ---- recurrence: 8 t-steps, 2 chains per thread
        #pragma unroll
        for (int tl = 0; tl < 8; ++tl) {
            const float x0 = ldsf[tl * 512 + bA * 32 + pA];
            const float x1 = ldsf[tl * 512 + (bA + 8) * 32 + pA];
            if (isA) {
                st0 = 0.5f * st0 + x0; c0 += x0 * st0;   // po update, then o*po
                st1 = 0.5f * st1 + x1; c1 += x1 * st1;
                ot[(tl * 16 + bA)     * 34 + pA] = f2bf(x0);
                ot[(tl * 16 + bA + 8) * 34 + pA] = f2bf(x1);
            } else {
                st0 = fminf(fmaxf(0.5f * st0 + x0, 0.f), 1.f);
                st1 = fminf(fmaxf(0.5f * st1 + x1, 0.f), 1.f);
                ot[(tl * 16 + bA)     * 34 + pA] = f2bf(st0);
                ot[(tl * 16 + bA + 8) * 34 + pA] = f2bf(st1);
            }
        }
        __syncthreads();

        // ---- flush: 128 contiguous k per p-row, 16-B vector stores
        const int pf = tid >> 3;             // 0..31
        const int c8 = tid & 7;
        #pragma unroll
        for (int i = 0; i < 2; ++i) {
            const int ch = c8 + i * 8;       // 16-B chunk 0..15
            ushort8 v;
            #pragma unroll
            for (int s = 0; s < 8; ++s) v[s] = ot[(ch * 8 + s) * 34 + pf];
            *(ushort8*)&dst[(size_t)(p0 + pf) * K_TOT + T0 * 16 + ch * 8] = v;
        }
    }

    if (isA) {
        cbuf[bA][pA] = c0 + c1;              // partial over b in {bA, bA+8}
        __syncthreads();
        if (tid < 32) {
            float s = 0.f;
            #pragma unroll
            for (int r = 0; r < 8; ++r) s += cbuf[r][tid];
            coef[p0 + tid] = s;
        }
    }
}

// ---------------------------------------------------------------------------
// bf16 MFMA GEMM: 128x128 tile, BK=32, 4 waves, 4x4 16x16x32 tiles,
// glds width-16 staging, XOR chunk swizzle (conflict-free, verified R3).
#define BM 128
#define BN 128
#define BK 32

__global__ __launch_bounds__(256) void stdp_gemm_mfma(
        const unsigned short* __restrict__ AT,   // [POST][K] bf16 bits
        const unsigned short* __restrict__ BT,   // [PRE][K]  bf16 bits
        const float* __restrict__ W,             // [POST][PRE]
        const float* __restrict__ coef,          // [POST]
        float* __restrict__ Cout) {              // [POST][PRE]
    __shared__ unsigned short As[BM][BK];
    __shared__ unsigned short Bs[BN][BK];
    const int tid  = threadIdx.x;
    const int lane = tid & 63;
    const int wave = tid >> 6;
    const int wm = (wave >> 1) * 64;
    const int wn = (wave & 1) * 64;
    const int m0 = blockIdx.y * BM;
    const int n0 = blockIdx.x * BN;

    floatx4 acc[4][4];
    #pragma unroll
    for (int i = 0; i < 4; ++i)
        #pragma unroll
        for (int j = 0; j < 4; ++j)
            acc[i][j] = (floatx4){0.f, 0.f, 0.f, 0.f};

    const int srow = tid >> 2;
    const int qg   = (tid & 3) ^ ((srow >> 1) & 3);
    const unsigned short* ga = &AT[(size_t)(m0 + srow) * K_TOT + qg * 8];
    const unsigned short* gb = &BT[(size_t)(n0 + srow) * K_TOT + qg * 8];
    unsigned short* la = &As[0][0] + wave * 512;
    unsigned short* lb = &Bs[0][0] + wave * 512;

    const int rm  = lane & 15;
    const int q   = lane >> 4;
    const int kqs = (q ^ ((rm >> 1) & 3)) * 8;

    for (int k0 = 0; k0 < K_TOT; k0 += BK) {
        glds16(ga,              la);
        glds16(ga + 64 * K_TOT, la + 64 * BK);
        glds16(gb,              lb);
        glds16(gb + 64 * K_TOT, lb + 64 * BK);
        ga += BK; gb += BK;
        __syncthreads();

        bf16x8 af[4], bv[4];
        #pragma unroll
        for (int i = 0; i < 4; ++i) {
            af[i] = *(const bf16x8*)&As[wm + i * 16 + rm][kqs];
            bv[i] = *(const bf16x8*)&Bs[wn + i * 16 + rm][kqs];
        }
        #pragma unroll
        for (int mi = 0; mi < 4; ++mi)
            #pragma unroll
            for (int ni = 0; ni < 4; ++ni)
                acc[mi][ni] = __builtin_amdgcn_mfma_f32_16x16x32_bf16(
                    af[mi], bv[ni], acc[mi][ni], 0, 0, 0);
        __syncthreads();
    }

    // Epilogue: C = acc - coef[o]*W. C/D layout: col=lane&15, row=quad*4+reg.
    const int colp = n0 + wn + rm;
    const int rowb = m0 + wm + (lane >> 4) * 4;
    #pragma unroll
    for (int mi = 0; mi < 4; ++mi) {
        #pragma unroll
        for (int r = 0; r < 4; ++r) {
            const int o = rowb + mi * 16 + r;
            const float cf = coef[o];
            const float* wr = &W[(size_t)o * PRE];
            float* cr = &Cout[(size_t)o * PRE];
            #pragma unroll
            for (int ni = 0; ni < 4; ++ni) {
                const int p = colp + ni * 16;
                cr[p] = acc[mi][ni][r] - cf * wr[p];
            }
        }
    }
}

// ---------------------------------------------------------------------------
extern "C" void kernel_launch(void* const* d_in, const int* in_sizes, int n_in,
                              void* d_out, int out_size, void* d_ws, size_t ws_size,
                              hipStream_t stream) {
    const float* in_spikes  = (const float*)d_in[0];
    const float* out_spikes = (const float*)d_in[1];
    const float* weight     = (const float*)d_in[2];
    float* out = (float*)d_out;

    unsigned short* AT = (unsigned short*)d_ws;                 // 8 MB
    unsigned short* BT = AT + (size_t)POST * K_TOT;             // 8 MB
    float* coef = (float*)(BT + (size_t)PRE * K_TOT);           // 16 KB

    trace_convert<<<256, 256, 0, stream>>>(in_spikes, out_spikes, AT, BT, coef);

    dim3 grid(PRE / BN, POST / BM);
    stdp_gemm_mfma<<<grid, 256, 0, stream>>>(AT, BT, weight, coef, out);
}

// Round 6
// 184.235 us; speedup vs baseline: 1.0398x; 1.0398x over previous
//
#include <hip/hip_runtime.h>

// STDP delta_w on MI355X, bf16-MFMA formulation (2-dispatch, R4 structure).
//   term1: dW1[o,p] = sum_k O[k,o]*TP[k,p], K = T*B = 1024  -> bf16 MFMA GEMM
//   term2: -coef[o]*W[o,p], coef[o] = sum_k O[k,o]*PO[k,o]  -> fp32 epilogue
//
// R6: GEMM BK 32->64 (half the barriers, 32 MFMA/barrier, 32 KB LDS),
//     3-bit XOR chunk swizzle (slot = chunk ^ (row&7)) -> 2-way LDS reads.
// Converter identical to R4 (verified correct twice).
//
// ws: AT bf16 [4096][1024] (8MB) | BT bf16 [4096][1024] (8MB) | coef f32[4096]

#define T_STEPS 64
#define B_SZ    16
#define PRE     4096
#define POST    4096
#define K_TOT   1024

typedef __attribute__((ext_vector_type(8))) unsigned short ushort8;
typedef __attribute__((ext_vector_type(8))) __bf16 bf16x8;
typedef __attribute__((ext_vector_type(4))) float floatx4;

__device__ __forceinline__ unsigned short f2bf(float f) {
    unsigned int u = __float_as_uint(f);
    u += 0x7fff + ((u >> 16) & 1);          // round-to-nearest-even
    return (unsigned short)(u >> 16);
}

__device__ __forceinline__ void glds16(const void* g, void* l) {
    __builtin_amdgcn_global_load_lds((const __attribute__((address_space(1))) void*)g,
                                     (__attribute__((address_space(3))) void*)l,
                                     16, 0, 0);
}

// ---------------------------------------------------------------------------
// Converter: grid = 256 blocks (matrix = blk>>7, p-chunk = blk&127), 256 thr.
// (verbatim R4 — passed)
__global__ __launch_bounds__(256) void trace_convert(
        const float* __restrict__ in_spikes,
        const float* __restrict__ out_spikes,
        unsigned short* __restrict__ AT,
        unsigned short* __restrict__ BT,
        float* __restrict__ coef) {
    __shared__ float ldsf[4096];             // [8 t][16 b][32 p] fp32, 16 KB
    __shared__ unsigned short ot[128 * 34];  // [128 k][32 p + 2 pad], 8.5 KB
    __shared__ float cbuf[8][33];
    const int tid  = threadIdx.x;
    const int wave = tid >> 6;
    const int lane = tid & 63;
    const bool isA = blockIdx.x >= 128;
    const int p0 = (blockIdx.x & 127) * 32;
    const float* src = isA ? out_spikes : in_spikes;
    unsigned short* dst = isA ? AT : BT;

    const int bA = tid >> 5;                 // chains (bA, p) and (bA+8, p)
    const int pA = tid & 31;

    float st0 = 0.f, st1 = 0.f, c0 = 0.f, c1 = 0.f;

    for (int tc = 0; tc < 8; ++tc) {
        const int T0 = tc * 8;
        // ---- stage 16 b x 8 t x 32 p fp32 into LDS (4 glds x16B per wave)
        #pragma unroll
        for (int i = 0; i < 4; ++i) {
            const int q  = (wave * 4 + i) * 64 + lane;  // float-quad id 0..1023
            const int p  = (q & 7) * 4;
            const int b  = (q >> 3) & 15;
            const int tl = q >> 7;
            const float* g = src + ((size_t)((T0 + tl) * 16 + b)) * 4096 + p0 + p;
            glds16(g, (char*)ldsf + (size_t)(wave * 4 + i) * 1024);
        }
        __syncthreads();                     // drains vmcnt

        // ---- recurrence: 8 t-steps, 2 chains per thread
        #pragma unroll
        for (int tl = 0; tl < 8; ++tl) {
            const float x0 = ldsf[tl * 512 + bA * 32 + pA];
            const float x1 = ldsf[tl * 512 + (bA + 8) * 32 + pA];
            if (isA) {
                st0 = 0.5f * st0 + x0; c0 += x0 * st0;   // po update, then o*po
                st1 = 0.5f * st1 + x1; c1 += x1 * st1;
                ot[(tl * 16 + bA)     * 34 + pA] = f2bf(x0);
                ot[(tl * 16 + bA + 8) * 34 + pA] = f2bf(x1);
            } else {
                st0 = fminf(fmaxf(0.5f * st0 + x0, 0.f), 1.f);
                st1 = fminf(fmaxf(0.5f * st1 + x1, 0.f), 1.f);
                ot[(tl * 16 + bA)     * 34 + pA] = f2bf(st0);
                ot[(tl * 16 + bA + 8) * 34 + pA] = f2bf(st1);
            }
        }
        __syncthreads();

        // ---- flush: 128 contiguous k per p-row, 16-B vector stores
        const int pf = tid >> 3;             // 0..31
        const int c8 = tid & 7;
        #pragma unroll
        for (int i = 0; i < 2; ++i) {
            const int ch = c8 + i * 8;       // 16-B chunk 0..15
            ushort8 v;
            #pragma unroll
            for (int s = 0; s < 8; ++s) v[s] = ot[(ch * 8 + s) * 34 + pf];
            *(ushort8*)&dst[(size_t)(p0 + pf) * K_TOT + T0 * 16 + ch * 8] = v;
        }
    }

    if (isA) {
        cbuf[bA][pA] = c0 + c1;              // partial over b in {bA, bA+8}
        __syncthreads();
        if (tid < 32) {
            float s = 0.f;
            #pragma unroll
            for (int r = 0; r < 8; ++r) s += cbuf[r][tid];
            coef[p0 + tid] = s;
        }
    }
}

// ---------------------------------------------------------------------------
// bf16 MFMA GEMM: 128x128 tile, BK=64, 4 waves, 4x4 16x16x32 tiles x 2 halves,
// glds width-16 staging, 3-bit XOR chunk swizzle.
#define BK 64

__global__ __launch_bounds__(256) void stdp_gemm_mfma(
        const unsigned short* __restrict__ AT,   // [POST][K] bf16 bits
        const unsigned short* __restrict__ BT,   // [PRE][K]  bf16 bits
        const float* __restrict__ W,             // [POST][PRE]
        const float* __restrict__ coef,          // [POST]
        float* __restrict__ Cout) {              // [POST][PRE]
    __shared__ unsigned short As[128][BK];       // 16 KB, rows = 128 B = 8 chunks
    __shared__ unsigned short Bs[128][BK];
    const int tid  = threadIdx.x;
    const int lane = tid & 63;
    const int wave = tid >> 6;
    const int wm = (wave >> 1) * 64;
    const int wn = (wave & 1) * 64;
    const int m0 = blockIdx.y * 128;
    const int n0 = blockIdx.x * 128;

    floatx4 acc[4][4];
    #pragma unroll
    for (int i = 0; i < 4; ++i)
        #pragma unroll
        for (int j = 0; j < 4; ++j)
            acc[i][j] = (floatx4){0.f, 0.f, 0.f, 0.f};

    // Staging: thread tid -> row srow = tid>>3 (+32 per instr), LDS slot tid&7,
    // which receives global chunk (tid&7) ^ (row&7).
    const int srow = tid >> 3;                   // 0..31
    const int qg   = (tid & 7) ^ (srow & 7);
    const unsigned short* ga = &AT[(size_t)(m0 + srow) * K_TOT + qg * 8];
    const unsigned short* gb = &BT[(size_t)(n0 + srow) * K_TOT + qg * 8];
    char* laB = (char*)&As[0][0] + wave * 1024;  // wave-uniform base
    char* lbB = (char*)&Bs[0][0] + wave * 1024;

    const int rm = lane & 15;                    // fragment row (m or n)
    const int q  = lane >> 4;                    // k-quad within half
    const int sw = rm & 7;                       // read-side swizzle

    for (int k0 = 0; k0 < K_TOT; k0 += BK) {
        #pragma unroll
        for (int i = 0; i < 4; ++i) {            // rows i*32 .. i*32+31
            glds16(ga + (size_t)i * 32 * K_TOT, laB + i * 4096);
            glds16(gb + (size_t)i * 32 * K_TOT, lbB + i * 4096);
        }
        ga += BK; gb += BK;
        __syncthreads();

        #pragma unroll
        for (int h = 0; h < 2; ++h) {            // two 32-k halves
            const int ks = ((h * 4 + q) ^ sw) * 8;
            bf16x8 af[4], bv[4];
            #pragma unroll
            for (int i = 0; i < 4; ++i) {
                af[i] = *(const bf16x8*)&As[wm + i * 16 + rm][ks];
                bv[i] = *(const bf16x8*)&Bs[wn + i * 16 + rm][ks];
            }
            #pragma unroll
            for (int mi = 0; mi < 4; ++mi)
                #pragma unroll
                for (int ni = 0; ni < 4; ++ni)
                    acc[mi][ni] = __builtin_amdgcn_mfma_f32_16x16x32_bf16(
                        af[mi], bv[ni], acc[mi][ni], 0, 0, 0);
        }
        __syncthreads();
    }

    // Epilogue: C = acc - coef[o]*W. C/D layout: col=lane&15, row=quad*4+reg.
    const int colp = n0 + wn + rm;
    const int rowb = m0 + wm + (lane >> 4) * 4;
    #pragma unroll
    for (int mi = 0; mi < 4; ++mi) {
        #pragma unroll
        for (int r = 0; r < 4; ++r) {
            const int o = rowb + mi * 16 + r;
            const float cf = coef[o];
            const float* wr = &W[(size_t)o * PRE];
            float* cr = &Cout[(size_t)o * PRE];
            #pragma unroll
            for (int ni = 0; ni < 4; ++ni) {
                const int p = colp + ni * 16;
                cr[p] = acc[mi][ni][r] - cf * wr[p];
            }
        }
    }
}

// ---------------------------------------------------------------------------
extern "C" void kernel_launch(void* const* d_in, const int* in_sizes, int n_in,
                              void* d_out, int out_size, void* d_ws, size_t ws_size,
                              hipStream_t stream) {
    const float* in_spikes  = (const float*)d_in[0];
    const float* out_spikes = (const float*)d_in[1];
    const float* weight     = (const float*)d_in[2];
    float* out = (float*)d_out;

    unsigned short* AT = (unsigned short*)d_ws;                 // 8 MB
    unsigned short* BT = AT + (size_t)POST * K_TOT;             // 8 MB
    float* coef = (float*)(BT + (size_t)PRE * K_TOT);           // 16 KB

    trace_convert<<<256, 256, 0, stream>>>(in_spikes, out_spikes, AT, BT, coef);

    dim3 grid(PRE / 128, POST / 128);
    stdp_gemm_mfma<<<grid, 256, 0, stream>>>(AT, BT, weight, coef, out);
}